// Round 19
// baseline (62.799 us; speedup 1.0000x reference)
//
#include <hip/hip_runtime.h>

typedef unsigned short u16;
typedef unsigned int   u32;
typedef u16   u16x8 __attribute__((ext_vector_type(8)));
typedef float f32x4 __attribute__((ext_vector_type(4)));
typedef float f32x16 __attribute__((ext_vector_type(16)));
typedef __bf16 bf16x8 __attribute__((ext_vector_type(8)));
typedef u32   u32x4 __attribute__((ext_vector_type(4)));

#define QSCALE  0.18033688011112f     // 0.125 * log2(e): scores in exp2 units
#define BM_OPEN  -28.8539008177793f   // -20 * log2(e)
#define BM_MASK  -14455.8043097f      // -(10000+20) * log2(e)

__device__ __forceinline__ u16 f2bf(float x){
  __bf16 h = (__bf16)x;
  return __builtin_bit_cast(u16, h);
}
__device__ __forceinline__ f32x16 mfma32(u16x8 a, u16x8 b, f32x16 c){
  return __builtin_amdgcn_mfma_f32_32x32x16_bf16(
      __builtin_bit_cast(bf16x8, a), __builtin_bit_cast(bf16x8, b), c, 0, 0, 0);
}
__device__ __forceinline__ void gld16(const void* g, void* l){
  __builtin_amdgcn_global_load_lds(
      (const __attribute__((address_space(1))) u32*)g,
      (__attribute__((address_space(3))) u32*)l, 16, 0, 0);
}
__device__ __forceinline__ u32 cvtpk(float lo, float hi){
  u32 d;
  asm("v_cvt_pk_bf16_f32 %0, %1, %2" : "=v"(d) : "v"(lo), "v"(hi));
  return d;
}
__device__ __forceinline__ void plswap(u32 &x, u32 &y){
  asm("v_permlane32_swap_b32 %0, %1" : "+v"(x), "+v"(y));
}

// ===================== layout (unchanged image) =====================
// Per (b,h,kt) tile: 8192 u16 = [K 4096 | V 4096], 16384 B.
//  K: K[key][d] bf16. Row=key, stride 64 u16 (128 B). chunk c at c ^ (key&7).
//  V: V^T[d][s] u32 (s,s+1)-pairs. Row=d, 32 u32. chunk c at c ^ (d&7).

// ===================== pre-pass: f32 KV -> swizzled bf16 tile image ==========
__global__ __launch_bounds__(256, 4)
void prepass(const float* __restrict__ KV, const int* __restrict__ MASK,
             u16* __restrict__ IMG, float* __restrict__ BIASM)
{
  const int tid = threadIdx.x;
  const int bid = blockIdx.x;        // ((b*16+h)*32 + kt)
  const int kt = bid & 31;
  const int h  = (bid >> 5) & 15;
  const int b  = bid >> 9;
  const int kb = kt*64;
  const size_t kv_b = (size_t)b*(2048u*2048u);
  u16* tile = IMG + (size_t)bid * 8192;

  {
    const int skey = tid >> 2, scp = tid & 3;
    const float* kp = KV + kv_b + (size_t)(kb + skey)*2048 + h*64 + 16*scp;
    f32x4 f0 = *(const f32x4*)(kp);
    f32x4 f1 = *(const f32x4*)(kp + 4);
    f32x4 f2 = *(const f32x4*)(kp + 8);
    f32x4 f3 = *(const f32x4*)(kp + 12);
    u16x8 c0, c1;
    #pragma unroll
    for (int e = 0; e < 4; ++e){
      c0[e] = f2bf(f0[e]); c0[e+4] = f2bf(f1[e]);
      c1[e] = f2bf(f2[e]); c1[e+4] = f2bf(f3[e]);
    }
    const int idx0 = skey*64 + (((2*scp) ^ (skey & 7)) << 3);
    *(u16x8*)&tile[idx0]     = c0;
    *(u16x8*)&tile[idx0 ^ 8] = c1;
  }
  {
    const int sdb = tid & 7, ssp = tid >> 3;
    const float* vp = KV + kv_b + (size_t)(kb + 2*ssp)*2048 + 1024 + h*64 + 8*sdb;
    f32x4 r0a = *(const f32x4*)(vp);
    f32x4 r0b = *(const f32x4*)(vp + 4);
    f32x4 r1a = *(const f32x4*)(vp + 2048);
    f32x4 r1b = *(const f32x4*)(vp + 2048 + 4);
    u32* vimg = (u32*)(tile + 4096);
    const int wc = ssp >> 2, wi = ssp & 3;
    #pragma unroll
    for (int j = 0; j < 4; ++j){
      const int d0 = 8*sdb + j;
      const int d1 = d0 + 4;
      vimg[d0*32 + ((wc ^ (d0 & 7)) << 2) + wi] = (u32)f2bf(r0a[j]) | ((u32)f2bf(r1a[j]) << 16);
      vimg[d1*32 + ((wc ^ (d1 & 7)) << 2) + wi] = (u32)f2bf(r0b[j]) | ((u32)f2bf(r1b[j]) << 16);
    }
  }
  if (h == 0 && tid < 64){
    const int s = kb + tid;
    BIASM[b*2048 + s] = MASK[b*2048 + s] ? BM_OPEN : BM_MASK;
  }
}

// ===================== main: 32x32 MFMA flash attention ======================
// Grid 512. Block = 4 waves x 32 q-rows = 128 rows (256 threads).
// r16's verified COMPUTE (in-register P via cvt_pk+permlane32_swap).
// DOUBLE-buffered KV + plain __syncthreads (r12's proven sync pattern).
// LDS = 2x16384 + 8192 = 40960 B -> 3 blocks/CU (12 waves, 3 waves/SIMD).
template<int PRE>
__global__ __launch_bounds__(256, 3)
void attn_main(const float* __restrict__ Q, const float* __restrict__ KV,
               const int* __restrict__ MASK, const u16* __restrict__ IMG,
               const float* __restrict__ BIASM, float* __restrict__ OUT)
{
  __shared__ __align__(16) u16 KVbuf[2][8192];   // 32 KB
  __shared__ __align__(16) float BiasLds[2048];  // 8 KB

  const int tid  = threadIdx.x;
  const int lane = tid & 63;
  const int hi   = lane >> 5;     // lane half
  const int lq   = lane & 31;     // q (and MFMA row) index

  const int bid0 = blockIdx.x;
  const int bid  = (bid0 & 7)*64 + (bid0 >> 3);   // XCD swizzle (bijective 8x64)
  const int qt  = bid & 15;
  const int h   = (bid >> 4) & 15;
  const int b   = bid >> 8;

  const int w    = tid >> 6;
  const int qbase = qt*128 + w*32;
  const size_t q_b  = (size_t)b * (2048u*1024u);
  const size_t kv_b = (size_t)b * (2048u*2048u);

  const int sw7 = lq & 7;

  // ---- Q fragments: lane holds Q[q=lq][d=16kc+8hi+e] ----
  u16x8 Qf[4];
  {
    const int qrow = qbase + lq;
    const float* qp = Q + q_b + (size_t)qrow*1024 + h*64 + 8*hi;
    #pragma unroll
    for (int kc = 0; kc < 4; ++kc){
      f32x4 a = *(const f32x4*)(qp + 16*kc);
      f32x4 c = *(const f32x4*)(qp + 16*kc + 4);
      u16x8 v;
      #pragma unroll
      for (int e = 0; e < 4; ++e){
        v[e]     = f2bf(a[e] * QSCALE);
        v[e + 4] = f2bf(c[e] * QSCALE);
      }
      Qf[kc] = v;
    }
  }

  f32x16 Oa[2];
  #pragma unroll
  for (int dt = 0; dt < 2; ++dt)
    #pragma unroll
    for (int r = 0; r < 16; ++r) Oa[dt][r] = 0.f;
  float lrun = 0.f;

  // staging constants
  const char* img0 = (const char*)IMG + (size_t)((b*16 + h)*32) * 16384;
  const int so = tid*16;
  const int skey = tid >> 2, scp = tid & 3;   // PRE=0 K
  const int sdb  = tid & 7,  ssp = tid >> 3;  // PRE=0 V
  const float* kp0 = KV + kv_b + (size_t)skey*2048 + h*64 + 16*scp;
  const float* vp0 = KV + kv_b + (size_t)(2*ssp)*2048 + 1024 + h*64 + 8*sdb;
  f32x4 kf0, kf1, kf2, kf3, va, vb2, vc, vd;   // PRE=0 staging regs

#define STAGE_ISSUE(T, DST) do{                                               \
    const char* g_ = img0 + (size_t)(T)*16384;                                \
    char* l_ = (char*)(DST);                                                  \
    gld16(g_+so,        l_+so);                                               \
    gld16(g_+so+4096,   l_+so+4096);                                          \
    gld16(g_+so+8192,   l_+so+8192);                                          \
    gld16(g_+so+12288,  l_+so+12288);                                         \
  }while(0)

#define BIAS_STAGE() do{                                                      \
    const char* gb_ = (const char*)BIASM + (size_t)b*8192;                    \
    char* lb_ = (char*)BiasLds;                                               \
    gld16(gb_+so,      lb_+so);                                               \
    gld16(gb_+so+4096, lb_+so+4096);                                          \
  }while(0)

#define STAGE_REG(T) do{                                                      \
    const float* kp_ = kp0 + (size_t)(T)*64*2048;                             \
    kf0=*(const f32x4*)(kp_);   kf1=*(const f32x4*)(kp_+4);                   \
    kf2=*(const f32x4*)(kp_+8); kf3=*(const f32x4*)(kp_+12);                  \
    const float* vp_ = vp0 + (size_t)(T)*64*2048;                             \
    va=*(const f32x4*)(vp_);      vb2=*(const f32x4*)(vp_+4);                 \
    vc=*(const f32x4*)(vp_+2048); vd =*(const f32x4*)(vp_+2048+4);            \
  }while(0)

#define STAGE_WRITE(DST) do{                                                  \
    u16x8 c0_, c1_;                                                           \
    _Pragma("unroll") for (int e_=0; e_<4; ++e_){                             \
      c0_[e_]=f2bf(kf0[e_]); c0_[e_+4]=f2bf(kf1[e_]);                         \
      c1_[e_]=f2bf(kf2[e_]); c1_[e_+4]=f2bf(kf3[e_]); }                       \
    const int kix_ = skey*64 + (((2*scp) ^ (skey & 7)) << 3);                 \
    *(u16x8*)&(DST)[kix_]     = c0_;                                          \
    *(u16x8*)&(DST)[kix_ ^ 8] = c1_;                                          \
    u32* vimg_ = (u32*)((DST)+4096);                                          \
    const int wc_ = ssp >> 2, wi_ = ssp & 3;                                  \
    _Pragma("unroll") for (int j_=0; j_<4; ++j_){                             \
      const int d0_=8*sdb+j_, d1_=d0_+4;                                      \
      vimg_[d0_*32 + ((wc_ ^ (d0_&7)) << 2) + wi_] = (u32)f2bf(va[j_])  | ((u32)f2bf(vc[j_])<<16); \
      vimg_[d1_*32 + ((wc_ ^ (d1_&7)) << 2) + wi_] = (u32)f2bf(vb2[j_]) | ((u32)f2bf(vd[j_])<<16); \
    }                                                                         \
  }while(0)

// r16's verified COMPUTE: S C-init from bias; QK (8 MFMA); exp2; cvt_pk +
// permlane -> P frags in registers; PV (8 MFMA). No P LDS round-trip.
#define COMPUTE(T, CUR) do{                                                   \
    const u16* Kb_ = (CUR);                                                   \
    const u32* vimg_ = (const u32*)((CUR) + 4096);                            \
    f32x16 S[2];                                                              \
    _Pragma("unroll") for (int ct = 0; ct < 2; ++ct){                         \
      _Pragma("unroll") for (int m = 0; m < 4; ++m){                          \
        f32x4 bq;                                                             \
        if constexpr (PRE){                                                   \
          bq = *(const f32x4*)&BiasLds[(T)*64 + 32*ct + 8*m + 4*hi];          \
        } else {                                                              \
          const int4 mv = *(const int4*)(MASK + b*2048 + (T)*64 + 32*ct + 8*m + 4*hi); \
          bq[0] = mv.x ? BM_OPEN : BM_MASK;                                   \
          bq[1] = mv.y ? BM_OPEN : BM_MASK;                                   \
          bq[2] = mv.z ? BM_OPEN : BM_MASK;                                   \
          bq[3] = mv.w ? BM_OPEN : BM_MASK;                                   \
        }                                                                     \
        S[ct][4*m+0] = bq[0]; S[ct][4*m+1] = bq[1];                           \
        S[ct][4*m+2] = bq[2]; S[ct][4*m+3] = bq[3];                           \
      }                                                                       \
    }                                                                         \
    __builtin_amdgcn_s_setprio(1);                                            \
    _Pragma("unroll") for (int ct = 0; ct < 2; ++ct){                         \
      _Pragma("unroll") for (int kc = 0; kc < 4; ++kc){                       \
        u16x8 kf = *(const u16x8*)&Kb_[(32*ct + lq)*64 + (((2*kc+hi)^sw7)<<3)]; \
        S[ct] = mfma32(kf, Qf[kc], S[ct]);                                    \
      }                                                                       \
    }                                                                         \
    __builtin_amdgcn_s_setprio(0);                                            \
    u32 pa[2][4], pb[2][4];                                                   \
    float ps = 0.f;                                                           \
    _Pragma("unroll") for (int ct = 0; ct < 2; ++ct){                         \
      _Pragma("unroll") for (int m = 0; m < 4; ++m){                          \
        const float p0 = __builtin_amdgcn_exp2f(S[ct][4*m+0]);                \
        const float p1 = __builtin_amdgcn_exp2f(S[ct][4*m+1]);                \
        const float p2 = __builtin_amdgcn_exp2f(S[ct][4*m+2]);                \
        const float p3 = __builtin_amdgcn_exp2f(S[ct][4*m+3]);                \
        ps += (p0 + p1) + (p2 + p3);                                          \
        pa[ct][m] = cvtpk(p0, p1);                                            \
        pb[ct][m] = cvtpk(p2, p3);                                            \
      }                                                                       \
    }                                                                         \
    lrun += ps;                                                               \
    u16x8 Pf[4];                                                              \
    _Pragma("unroll") for (int ct = 0; ct < 2; ++ct){                         \
      plswap(pa[ct][0], pa[ct][1]);  plswap(pb[ct][0], pb[ct][1]);            \
      plswap(pa[ct][2], pa[ct][3]);  plswap(pb[ct][2], pb[ct][3]);            \
      u32x4 f0_ = { pa[ct][0], pb[ct][0], pa[ct][1], pb[ct][1] };             \
      u32x4 f1_ = { pa[ct][2], pb[ct][2], pa[ct][3], pb[ct][3] };             \
      Pf[2*ct+0] = __builtin_bit_cast(u16x8, f0_);                            \
      Pf[2*ct+1] = __builtin_bit_cast(u16x8, f1_);                            \
    }                                                                         \
    __builtin_amdgcn_s_setprio(1);                                            \
    _Pragma("unroll") for (int dt = 0; dt < 2; ++dt){                         \
      _Pragma("unroll") for (int sc = 0; sc < 4; ++sc){                       \
        u32x4 vv = *(const u32x4*)&vimg_[(32*dt + lq)*32 + (((2*sc+hi)^sw7)<<2)]; \
        Oa[dt] = mfma32(__builtin_bit_cast(u16x8, vv), Pf[sc], Oa[dt]);       \
      }                                                                       \
    }                                                                         \
    __builtin_amdgcn_s_setprio(0);                                            \
  }while(0)

  // ---- prologue ----
  if constexpr (PRE){
    BIAS_STAGE();
    STAGE_ISSUE(0, &KVbuf[0][0]);
  } else {
    STAGE_REG(0);
    STAGE_WRITE(&KVbuf[0][0]);
  }
  __syncthreads();   // drains DMA (vmcnt) + joins waves

  // ---- main loop: double-buffer, stage t+1 while computing t ----
  for (int t = 0; t < 32; ++t){
    if (t < 31){
      if constexpr (PRE) STAGE_ISSUE(t+1, &KVbuf[(t+1) & 1][0]);
      else               STAGE_REG(t+1);
    }
    COMPUTE(t, &KVbuf[t & 1][0]);
    if (t < 31){
      if constexpr (!PRE) STAGE_WRITE(&KVbuf[(t+1) & 1][0]);
      __syncthreads();
    }
  }

  // ---- epilogue: combine lane halves' l, normalize, store f32 ----
  {
    float l_ = lrun + __shfl_xor(lrun, 32, 64);
    const float inv = 1.f / l_;
    const int qrow = qbase + lq;
    float* op = OUT + q_b + (size_t)qrow*1024 + h*64;
    #pragma unroll
    for (int dt = 0; dt < 2; ++dt){
      #pragma unroll
      for (int m = 0; m < 4; ++m){
        f32x4 ov;
        ov[0] = Oa[dt][4*m+0] * inv;
        ov[1] = Oa[dt][4*m+1] * inv;
        ov[2] = Oa[dt][4*m+2] * inv;
        ov[3] = Oa[dt][4*m+3] * inv;
        *(f32x4*)(op + 32*dt + 8*m + 4*hi) = ov;
      }
    }
  }
#undef STAGE_ISSUE
#undef BIAS_STAGE
#undef STAGE_REG
#undef STAGE_WRITE
#undef COMPUTE
}

extern "C" void kernel_launch(void* const* d_in, const int* in_sizes, int n_in,
                              void* d_out, int out_size, void* d_ws, size_t ws_size,
                              hipStream_t stream)
{
  const float* Q  = nullptr;
  const float* KV = nullptr;
  const int*   M  = nullptr;
  for (int i = 0; i < n_in; ++i){
    if      (in_sizes[i] == 4194304) Q  = (const float*)d_in[i];
    else if (in_sizes[i] == 8388608) KV = (const float*)d_in[i];
    else if (in_sizes[i] == 4096)    M  = (const int*)d_in[i];
  }
  if (!Q)  Q  = (const float*)d_in[0];
  if (!KV) KV = (const float*)d_in[1];
  if (!M)  M  = (const int*)d_in[2];
  float* O = (float*)d_out;

  const size_t NEED = 16384ull + 1024ull*16384ull;   // biasM + KV image (16.8 MB)
  if (ws_size >= NEED){
    float* biasm = (float*)d_ws;
    u16*   img   = (u16*)((char*)d_ws + 16384);
    prepass<<<dim3(1024), dim3(256), 0, stream>>>(KV, M, img, biasm);
    attn_main<1><<<dim3(512), dim3(256), 0, stream>>>(Q, KV, M, img, biasm, O);
  } else {
    attn_main<0><<<dim3(512), dim3(256), 0, stream>>>(Q, KV, M, nullptr, nullptr, O);
  }
}

// Round 20
// 60.739 us; speedup vs baseline: 1.0339x; 1.0339x over previous
//
#include <hip/hip_runtime.h>

typedef unsigned short u16;
typedef unsigned int   u32;
typedef u16   u16x8 __attribute__((ext_vector_type(8)));
typedef float f32x4 __attribute__((ext_vector_type(4)));
typedef float f32x16 __attribute__((ext_vector_type(16)));
typedef __bf16 bf16x8 __attribute__((ext_vector_type(8)));
typedef u32   u32x4 __attribute__((ext_vector_type(4)));

#define QSCALE  0.18033688011112f     // 0.125 * log2(e): scores in exp2 units
#define BM_OPEN  -28.8539008177793f   // -20 * log2(e)
#define BM_MASK  -14455.8043097f      // -(10000+20) * log2(e)

__device__ __forceinline__ u16 f2bf(float x){
  __bf16 h = (__bf16)x;
  return __builtin_bit_cast(u16, h);
}
__device__ __forceinline__ f32x16 mfma32(u16x8 a, u16x8 b, f32x16 c){
  return __builtin_amdgcn_mfma_f32_32x32x16_bf16(
      __builtin_bit_cast(bf16x8, a), __builtin_bit_cast(bf16x8, b), c, 0, 0, 0);
}
__device__ __forceinline__ void gld16(const void* g, void* l){
  __builtin_amdgcn_global_load_lds(
      (const __attribute__((address_space(1))) u32*)g,
      (__attribute__((address_space(3))) u32*)l, 16, 0, 0);
}
__device__ __forceinline__ u32 cvtpk(float lo, float hi){
  u32 d;
  asm("v_cvt_pk_bf16_f32 %0, %1, %2" : "=v"(d) : "v"(lo), "v"(hi));
  return d;
}
__device__ __forceinline__ void plswap(u32 &x, u32 &y){
  asm("v_permlane32_swap_b32 %0, %1" : "+v"(x), "+v"(y));
}

// ===================== layout (unchanged image) =====================
// Per (b,h,kt) tile: 8192 u16 = [K 4096 | V 4096], 16384 B.
//  K: K[key][d] bf16. Row=key, stride 64 u16 (128 B). chunk c at c ^ (key&7).
//  V: V^T[d][s] u32 (s,s+1)-pairs. Row=d, 32 u32. chunk c at c ^ (d&7).

// ===================== pre-pass: f32 KV -> swizzled bf16 tile image ==========
__global__ __launch_bounds__(256, 4)
void prepass(const float* __restrict__ KV, const int* __restrict__ MASK,
             u16* __restrict__ IMG, float* __restrict__ BIASM)
{
  const int tid = threadIdx.x;
  const int bid = blockIdx.x;        // ((b*16+h)*32 + kt)
  const int kt = bid & 31;
  const int h  = (bid >> 5) & 15;
  const int b  = bid >> 9;
  const int kb = kt*64;
  const size_t kv_b = (size_t)b*(2048u*2048u);
  u16* tile = IMG + (size_t)bid * 8192;

  {
    const int skey = tid >> 2, scp = tid & 3;
    const float* kp = KV + kv_b + (size_t)(kb + skey)*2048 + h*64 + 16*scp;
    f32x4 f0 = *(const f32x4*)(kp);
    f32x4 f1 = *(const f32x4*)(kp + 4);
    f32x4 f2 = *(const f32x4*)(kp + 8);
    f32x4 f3 = *(const f32x4*)(kp + 12);
    u16x8 c0, c1;
    #pragma unroll
    for (int e = 0; e < 4; ++e){
      c0[e] = f2bf(f0[e]); c0[e+4] = f2bf(f1[e]);
      c1[e] = f2bf(f2[e]); c1[e+4] = f2bf(f3[e]);
    }
    const int idx0 = skey*64 + (((2*scp) ^ (skey & 7)) << 3);
    *(u16x8*)&tile[idx0]     = c0;
    *(u16x8*)&tile[idx0 ^ 8] = c1;
  }
  {
    const int sdb = tid & 7, ssp = tid >> 3;
    const float* vp = KV + kv_b + (size_t)(kb + 2*ssp)*2048 + 1024 + h*64 + 8*sdb;
    f32x4 r0a = *(const f32x4*)(vp);
    f32x4 r0b = *(const f32x4*)(vp + 4);
    f32x4 r1a = *(const f32x4*)(vp + 2048);
    f32x4 r1b = *(const f32x4*)(vp + 2048 + 4);
    u32* vimg = (u32*)(tile + 4096);
    const int wc = ssp >> 2, wi = ssp & 3;
    #pragma unroll
    for (int j = 0; j < 4; ++j){
      const int d0 = 8*sdb + j;
      const int d1 = d0 + 4;
      vimg[d0*32 + ((wc ^ (d0 & 7)) << 2) + wi] = (u32)f2bf(r0a[j]) | ((u32)f2bf(r1a[j]) << 16);
      vimg[d1*32 + ((wc ^ (d1 & 7)) << 2) + wi] = (u32)f2bf(r0b[j]) | ((u32)f2bf(r1b[j]) << 16);
    }
  }
  if (h == 0 && tid < 64){
    const int s = kb + tid;
    BIASM[b*2048 + s] = MASK[b*2048 + s] ? BM_OPEN : BM_MASK;
  }
}

// ===================== main: 32x32 MFMA flash attention ======================
// Grid 512. Block = 4 waves x 32 q-rows = 128 rows (256 threads).
// TWO independent tile-streams per barrier interval: tiles (2u, 2u+1) with
// separate S/P and separate O accumulators (Oa0/Oa1, summed in epilogue).
// Phase-interleaved (QK_A;QK_B; SM_A;SM_B; PV_A;PV_B) -> 4 independent MFMA
// chains + 64-wide exp2 batches. Quad-buffered KV, plain __syncthreads.
template<int PRE>
__global__ __launch_bounds__(256, 2)
void attn_main(const float* __restrict__ Q, const float* __restrict__ KV,
               const int* __restrict__ MASK, const u16* __restrict__ IMG,
               const float* __restrict__ BIASM, float* __restrict__ OUT)
{
  __shared__ __align__(16) u16 KVbuf[4][8192];   // 64 KB (PRE=0 uses [0],[1])
  __shared__ __align__(16) float BiasLds[2048];  // 8 KB

  const int tid  = threadIdx.x;
  const int lane = tid & 63;
  const int hi   = lane >> 5;     // lane half
  const int lq   = lane & 31;     // q (and MFMA row) index

  const int bid0 = blockIdx.x;
  const int bid  = (bid0 & 7)*64 + (bid0 >> 3);   // XCD swizzle (bijective 8x64)
  const int qt  = bid & 15;
  const int h   = (bid >> 4) & 15;
  const int b   = bid >> 8;

  const int w    = tid >> 6;
  const int qbase = qt*128 + w*32;
  const size_t q_b  = (size_t)b * (2048u*1024u);
  const size_t kv_b = (size_t)b * (2048u*2048u);

  const int sw7 = lq & 7;

  // ---- Q fragments: lane holds Q[q=lq][d=16kc+8hi+e] ----
  u16x8 Qf[4];
  {
    const int qrow = qbase + lq;
    const float* qp = Q + q_b + (size_t)qrow*1024 + h*64 + 8*hi;
    #pragma unroll
    for (int kc = 0; kc < 4; ++kc){
      f32x4 a = *(const f32x4*)(qp + 16*kc);
      f32x4 c = *(const f32x4*)(qp + 16*kc + 4);
      u16x8 v;
      #pragma unroll
      for (int e = 0; e < 4; ++e){
        v[e]     = f2bf(a[e] * QSCALE);
        v[e + 4] = f2bf(c[e] * QSCALE);
      }
      Qf[kc] = v;
    }
  }

  f32x16 Oa0[2], Oa1[2];
  #pragma unroll
  for (int dt = 0; dt < 2; ++dt)
    #pragma unroll
    for (int r = 0; r < 16; ++r){ Oa0[dt][r] = 0.f; Oa1[dt][r] = 0.f; }
  float lrun0 = 0.f, lrun1 = 0.f;

  // staging constants
  const char* img0 = (const char*)IMG + (size_t)((b*16 + h)*32) * 16384;
  const int so = tid*16;
  const int skey = tid >> 2, scp = tid & 3;   // PRE=0 K
  const int sdb  = tid & 7,  ssp = tid >> 3;  // PRE=0 V
  const float* kp0 = KV + kv_b + (size_t)skey*2048 + h*64 + 16*scp;
  const float* vp0 = KV + kv_b + (size_t)(2*ssp)*2048 + 1024 + h*64 + 8*sdb;
  f32x4 kf0, kf1, kf2, kf3, va, vb2, vc, vd;   // PRE=0 staging regs

#define STAGE_ISSUE(T, DST) do{                                               \
    const char* g_ = img0 + (size_t)(T)*16384;                                \
    char* l_ = (char*)(DST);                                                  \
    gld16(g_+so,        l_+so);                                               \
    gld16(g_+so+4096,   l_+so+4096);                                          \
    gld16(g_+so+8192,   l_+so+8192);                                          \
    gld16(g_+so+12288,  l_+so+12288);                                         \
  }while(0)

#define BIAS_STAGE() do{                                                      \
    const char* gb_ = (const char*)BIASM + (size_t)b*8192;                    \
    char* lb_ = (char*)BiasLds;                                               \
    gld16(gb_+so,      lb_+so);                                               \
    gld16(gb_+so+4096, lb_+so+4096);                                          \
  }while(0)

#define STAGE_REG(T) do{                                                      \
    const float* kp_ = kp0 + (size_t)(T)*64*2048;                             \
    kf0=*(const f32x4*)(kp_);   kf1=*(const f32x4*)(kp_+4);                   \
    kf2=*(const f32x4*)(kp_+8); kf3=*(const f32x4*)(kp_+12);                  \
    const float* vp_ = vp0 + (size_t)(T)*64*2048;                             \
    va=*(const f32x4*)(vp_);      vb2=*(const f32x4*)(vp_+4);                 \
    vc=*(const f32x4*)(vp_+2048); vd =*(const f32x4*)(vp_+2048+4);            \
  }while(0)

#define STAGE_WRITE(DST) do{                                                  \
    u16x8 c0_, c1_;                                                           \
    _Pragma("unroll") for (int e_=0; e_<4; ++e_){                             \
      c0_[e_]=f2bf(kf0[e_]); c0_[e_+4]=f2bf(kf1[e_]);                         \
      c1_[e_]=f2bf(kf2[e_]); c1_[e_+4]=f2bf(kf3[e_]); }                       \
    const int kix_ = skey*64 + (((2*scp) ^ (skey & 7)) << 3);                 \
    *(u16x8*)&(DST)[kix_]     = c0_;                                          \
    *(u16x8*)&(DST)[kix_ ^ 8] = c1_;                                          \
    u32* vimg_ = (u32*)((DST)+4096);                                          \
    const int wc_ = ssp >> 2, wi_ = ssp & 3;                                  \
    _Pragma("unroll") for (int j_=0; j_<4; ++j_){                             \
      const int d0_=8*sdb+j_, d1_=d0_+4;                                      \
      vimg_[d0_*32 + ((wc_ ^ (d0_&7)) << 2) + wi_] = (u32)f2bf(va[j_])  | ((u32)f2bf(vc[j_])<<16); \
      vimg_[d1_*32 + ((wc_ ^ (d1_&7)) << 2) + wi_] = (u32)f2bf(vb2[j_]) | ((u32)f2bf(vd[j_])<<16); \
    }                                                                         \
  }while(0)

// ---- phase macros (r16's verified per-tile math, stream-parameterized) ----
#define SINIT(T, SD) do{                                                      \
    _Pragma("unroll") for (int ct = 0; ct < 2; ++ct){                         \
      _Pragma("unroll") for (int m = 0; m < 4; ++m){                          \
        f32x4 bq;                                                             \
        if constexpr (PRE){                                                   \
          bq = *(const f32x4*)&BiasLds[(T)*64 + 32*ct + 8*m + 4*hi];          \
        } else {                                                              \
          const int4 mv = *(const int4*)(MASK + b*2048 + (T)*64 + 32*ct + 8*m + 4*hi); \
          bq[0] = mv.x ? BM_OPEN : BM_MASK;                                   \
          bq[1] = mv.y ? BM_OPEN : BM_MASK;                                   \
          bq[2] = mv.z ? BM_OPEN : BM_MASK;                                   \
          bq[3] = mv.w ? BM_OPEN : BM_MASK;                                   \
        }                                                                     \
        SD[ct][4*m+0] = bq[0]; SD[ct][4*m+1] = bq[1];                         \
        SD[ct][4*m+2] = bq[2]; SD[ct][4*m+3] = bq[3];                         \
      }                                                                       \
    }                                                                         \
  }while(0)

#define QK(CUR, SD) do{                                                       \
    const u16* Kb_ = (CUR);                                                   \
    _Pragma("unroll") for (int ct = 0; ct < 2; ++ct){                         \
      _Pragma("unroll") for (int kc = 0; kc < 4; ++kc){                       \
        u16x8 kf = *(const u16x8*)&Kb_[(32*ct + lq)*64 + (((2*kc+hi)^sw7)<<3)]; \
        SD[ct] = mfma32(kf, Qf[kc], SD[ct]);                                  \
      }                                                                       \
    }                                                                         \
  }while(0)

#define SM(SD, PFD, LR) do{                                                   \
    u32 pa[2][4], pb[2][4];                                                   \
    float ps = 0.f;                                                           \
    _Pragma("unroll") for (int ct = 0; ct < 2; ++ct){                         \
      _Pragma("unroll") for (int m = 0; m < 4; ++m){                          \
        const float p0 = __builtin_amdgcn_exp2f(SD[ct][4*m+0]);               \
        const float p1 = __builtin_amdgcn_exp2f(SD[ct][4*m+1]);               \
        const float p2 = __builtin_amdgcn_exp2f(SD[ct][4*m+2]);               \
        const float p3 = __builtin_amdgcn_exp2f(SD[ct][4*m+3]);               \
        ps += (p0 + p1) + (p2 + p3);                                          \
        pa[ct][m] = cvtpk(p0, p1);                                            \
        pb[ct][m] = cvtpk(p2, p3);                                            \
      }                                                                       \
    }                                                                         \
    LR += ps;                                                                 \
    _Pragma("unroll") for (int ct = 0; ct < 2; ++ct){                         \
      plswap(pa[ct][0], pa[ct][1]);  plswap(pb[ct][0], pb[ct][1]);            \
      plswap(pa[ct][2], pa[ct][3]);  plswap(pb[ct][2], pb[ct][3]);            \
      u32x4 f0_ = { pa[ct][0], pb[ct][0], pa[ct][1], pb[ct][1] };             \
      u32x4 f1_ = { pa[ct][2], pb[ct][2], pa[ct][3], pb[ct][3] };             \
      PFD[2*ct+0] = __builtin_bit_cast(u16x8, f0_);                           \
      PFD[2*ct+1] = __builtin_bit_cast(u16x8, f1_);                           \
    }                                                                         \
  }while(0)

#define PV(CUR, PFD, OA) do{                                                  \
    const u32* vimg_ = (const u32*)((CUR) + 4096);                            \
    _Pragma("unroll") for (int dt = 0; dt < 2; ++dt){                         \
      _Pragma("unroll") for (int sc = 0; sc < 4; ++sc){                       \
        u32x4 vv = *(const u32x4*)&vimg_[(32*dt + lq)*32 + (((2*sc+hi)^sw7)<<2)]; \
        OA[dt] = mfma32(__builtin_bit_cast(u16x8, vv), PFD[sc], OA[dt]);      \
      }                                                                       \
    }                                                                         \
  }while(0)

  if constexpr (PRE){
    // ---- prologue: bias + pair 0 (tiles 0,1) ----
    BIAS_STAGE();
    STAGE_ISSUE(0, &KVbuf[0][0]);
    STAGE_ISSUE(1, &KVbuf[1][0]);
    __syncthreads();   // drains DMA + joins waves

    // ---- 16 pair-iterations: compute (2u,2u+1), stage (2u+2,2u+3) ----
    for (int u = 0; u < 16; ++u){
      const int ps = (u & 1) << 1;                    // compute pair buffers
      u16* ca = &KVbuf[0][0] + ps*8192;
      u16* cb = ca + 8192;
      if (u < 15){
        u16* sa = &KVbuf[0][0] + (ps ^ 2)*8192;
        STAGE_ISSUE(2*u + 2, sa);
        STAGE_ISSUE(2*u + 3, sa + 8192);
      }
      f32x16 SA[2], SB[2];
      u16x8 PfA[4], PfB[4];
      SINIT(2*u,     SA);
      SINIT(2*u + 1, SB);
      __builtin_amdgcn_s_setprio(1);
      QK(ca, SA);
      QK(cb, SB);
      __builtin_amdgcn_s_setprio(0);
      SM(SA, PfA, lrun0);
      SM(SB, PfB, lrun1);
      __builtin_amdgcn_s_setprio(1);
      PV(ca, PfA, Oa0);
      PV(cb, PfB, Oa1);
      __builtin_amdgcn_s_setprio(0);
      if (u < 15) __syncthreads();
    }
  } else {
    // fallback: reg staging, double buffer, serial per tile (all into stream 0)
    STAGE_REG(0);
    STAGE_WRITE(&KVbuf[0][0]);
    __syncthreads();
    for (int t = 0; t < 32; ++t){
      if (t < 31) STAGE_REG(t+1);
      u16* cur = &KVbuf[t & 1][0];
      f32x16 SA[2];
      u16x8 PfA[4];
      SINIT(t, SA);
      QK(cur, SA);
      SM(SA, PfA, lrun0);
      PV(cur, PfA, Oa0);
      if (t < 31){
        STAGE_WRITE(&KVbuf[(t+1) & 1][0]);
        __syncthreads();
      }
    }
  }

  // ---- epilogue: merge streams, combine lane halves' l, normalize, store ----
  {
    const float lsum = lrun0 + lrun1;
    const float l_ = lsum + __shfl_xor(lsum, 32, 64);
    const float inv = 1.f / l_;
    const int qrow = qbase + lq;
    float* op = OUT + q_b + (size_t)qrow*1024 + h*64;
    #pragma unroll
    for (int dt = 0; dt < 2; ++dt){
      #pragma unroll
      for (int m = 0; m < 4; ++m){
        f32x4 ov;
        ov[0] = (Oa0[dt][4*m+0] + Oa1[dt][4*m+0]) * inv;
        ov[1] = (Oa0[dt][4*m+1] + Oa1[dt][4*m+1]) * inv;
        ov[2] = (Oa0[dt][4*m+2] + Oa1[dt][4*m+2]) * inv;
        ov[3] = (Oa0[dt][4*m+3] + Oa1[dt][4*m+3]) * inv;
        *(f32x4*)(op + 32*dt + 8*m + 4*hi) = ov;
      }
    }
  }
#undef STAGE_ISSUE
#undef BIAS_STAGE
#undef STAGE_REG
#undef STAGE_WRITE
#undef SINIT
#undef QK
#undef SM
#undef PV
}

extern "C" void kernel_launch(void* const* d_in, const int* in_sizes, int n_in,
                              void* d_out, int out_size, void* d_ws, size_t ws_size,
                              hipStream_t stream)
{
  const float* Q  = nullptr;
  const float* KV = nullptr;
  const int*   M  = nullptr;
  for (int i = 0; i < n_in; ++i){
    if      (in_sizes[i] == 4194304) Q  = (const float*)d_in[i];
    else if (in_sizes[i] == 8388608) KV = (const float*)d_in[i];
    else if (in_sizes[i] == 4096)    M  = (const int*)d_in[i];
  }
  if (!Q)  Q  = (const float*)d_in[0];
  if (!KV) KV = (const float*)d_in[1];
  if (!M)  M  = (const int*)d_in[2];
  float* O = (float*)d_out;

  const size_t NEED = 16384ull + 1024ull*16384ull;   // biasM + KV image (16.8 MB)
  if (ws_size >= NEED){
    float* biasm = (float*)d_ws;
    u16*   img   = (u16*)((char*)d_ws + 16384);
    prepass<<<dim3(1024), dim3(256), 0, stream>>>(KV, M, img, biasm);
    attn_main<1><<<dim3(512), dim3(256), 0, stream>>>(Q, KV, M, img, biasm, O);
  } else {
    attn_main<0><<<dim3(512), dim3(256), 0, stream>>>(Q, KV, M, nullptr, nullptr, O);
  }
}